// Round 5
// baseline (328.052 us; speedup 1.0000x reference)
//
#include <hip/hip_runtime.h>
#include <math.h>

#define EPSF 1e-8f
// f32 nearest to 2*pi
#define TWO_PI_F 6.28318530717958647692f

// ---------------------------------------------------------------------------
// EXACT path (verbatim from the verified 340us kernel, absmax 0.0039).
// Only used for pixel-quads containing a hue-wrap-neighborhood pixel
// (h ~ 1.0), where the reference's atan2-roundtrip can round h' to exactly
// 1.0f -> hi==6 -> the jnp.select default ZERO output. That discontinuity
// must be replicated bit-faithfully; everywhere else the roundtrip is
// algebraically the identity.
// ---------------------------------------------------------------------------
__device__ __forceinline__ void hvi_exact(float r, float g, float b, float k,
                                          float& ro, float& go, float& bo)
{
    float value = fmaxf(r, fmaxf(g, b));
    float vmin  = fminf(r, fminf(g, b));
    float diff  = value - vmin + EPSF;

    bool isR = (r == value);
    bool isG = (!isR) && (g == value);

    float num  = isR ? (g - b) : (isG ? (b - r) : (r - g));
    float offs = isR ? 0.0f   : (isG ? 2.0f    : 4.0f);
    float x    = num / diff;                 // IEEE divide (matches np)
    float hue6 = offs + x;
    if (isR && x < 0.0f) hue6 = x + 6.0f;    // np mod semantics
    if (vmin == value)   hue6 = 0.0f;
    float hue = hue6 / 6.0f;                 // 6.0/6.0 == 1.0 exactly

    float sat = (value == 0.0f) ? 0.0f : (value - vmin) / (value + EPSF);

    float sv = __sinf((value * 0.5f) * 3.14159265358979323846f) + EPSF;
    float cs = __expf(k * __logf(sv));

    float ang = TWO_PI_F * hue;
    float sh, ch;
    sincosf(ang, &sh, &ch);                  // precise libm

    float X = cs * sat * ch;
    float Y = cs * sat * sh;

    // ---- _phvit ----
    float H = fminf(fmaxf(X, -1.0f), 1.0f);
    float V = fminf(fmaxf(Y, -1.0f), 1.0f);
    float v = fminf(fmaxf(value, 0.0f), 1.0f);

    float csd = cs + EPSF;
    H = fminf(fmaxf(H / csd, -1.0f), 1.0f);
    V = fminf(fmaxf(V / csd, -1.0f), 1.0f);

    float t2 = atan2f(V, H) / TWO_PI_F;      // precise atan2 + IEEE divide
    float h  = (t2 < 0.0f) ? t2 + 1.0f : t2; // np mod(x, 1.0) -> can hit 1.0f
    float s  = fminf(fmaxf(sqrtf(H * H + V * V), 0.0f), 1.0f);

    float h6  = h * 6.0f;
    float hif = floorf(h6);
    float f   = h6 - hif;
    float pv  = v * (1.0f - s);
    float qv  = v * (1.0f - f * s);
    float tv  = v * (1.0f - (1.0f - f) * s);
    int hi = (int)hif;

    float rr = 0.0f, gg = 0.0f, bb = 0.0f;   // hi==6 falls through to zero
    rr = (hi == 0) ? v  : rr;  gg = (hi == 0) ? tv : gg;  bb = (hi == 0) ? pv : bb;
    rr = (hi == 1) ? qv : rr;  gg = (hi == 1) ? v  : gg;  bb = (hi == 1) ? pv : bb;
    rr = (hi == 2) ? pv : rr;  gg = (hi == 2) ? v  : gg;  bb = (hi == 2) ? tv : bb;
    rr = (hi == 3) ? pv : rr;  gg = (hi == 3) ? qv : gg;  bb = (hi == 3) ? v  : bb;
    rr = (hi == 4) ? tv : rr;  gg = (hi == 4) ? pv : gg;  bb = (hi == 4) ? v  : bb;
    rr = (hi == 5) ? v  : rr;  gg = (hi == 5) ? pv : gg;  bb = (hi == 5) ? qv : bb;

    ro = rr; go = gg; bo = bb;
}

// ---------------------------------------------------------------------------
// FAST path: _phvit(_hvit(rgb)) is algebraically the identity roundtrip,
// so output = hsv_reconstruct(h, sat, v) with:
//   p = v*(1-sat) = vmin            (exact)
//   q = v - sv*f,  t = vmin + sv*f  (sv = v - vmin; dropping the /(v+eps)
//                                    factor costs <= eps = 1e-8 absolute)
// All hi-bucket boundaries are continuous, so the ~1e-6 h jitter from the
// fast rcp only produces ~1e-6 output jitter. The ONLY discontinuity in the
// reference is the h'==1.0 rounding -> zero output, which requires
// h6 within ~2e-6 of 6.0; the band check (2e-5, 10x margin) routes those
// quads to the exact path.
// ---------------------------------------------------------------------------
#define BAND_THRESH 5.99998f

extern "C" __global__ void __launch_bounds__(256)
rgb_hvi_kernel(const float* __restrict__ img, const float* __restrict__ kptr,
               float* __restrict__ out, int ngroups)
{
    int i = blockIdx.x * blockDim.x + threadIdx.x;
    if (i >= ngroups) return;
    const float k = kptr[0];

    unsigned int q = (unsigned int)i << 2;        // pixel index
    unsigned int n = q >> 20;                     // image index
    unsigned int p = q & 1048575u;                // pixel within image
    size_t base = (size_t)n * 3145728u + p;

    const float4 R = *reinterpret_cast<const float4*>(img + base);
    const float4 G = *reinterpret_cast<const float4*>(img + base + 1048576);
    const float4 B = *reinterpret_cast<const float4*>(img + base + 2097152);

    const float rin[4] = { R.x, R.y, R.z, R.w };
    const float gin[4] = { G.x, G.y, G.z, G.w };
    const float bin[4] = { B.x, B.y, B.z, B.w };
    float ro[4], go[4], bo[4];

    bool band = false;
#pragma unroll
    for (int j = 0; j < 4; ++j) {
        float r = rin[j], g = gin[j], b = bin[j];

        float value = fmaxf(r, fmaxf(g, b));      // v_max3
        float vmin  = fminf(r, fminf(g, b));      // v_min3
        float sv    = value - vmin;

        bool isR = (r == value);
        bool isG = (!isR) && (g == value);

        float num  = isR ? (g - b) : (isG ? (b - r) : (r - g));
        float offs = isR ? 0.0f   : (isG ? 2.0f    : 4.0f);
        float x    = num * __builtin_amdgcn_rcpf(sv + EPSF);
        float h6   = offs + x;
        if (isR && x < 0.0f) h6 = x + 6.0f;       // np mod semantics (wrap)
        if (vmin == value)   h6 = 0.0f;

        band = band || (h6 > BAND_THRESH);

        float hif = floorf(h6);
        float f   = h6 - hif;
        int   hi  = (int)hif;                     // in [0,5] off-band

        float svf = sv * f;
        float v   = value;
        float pv  = vmin;                         // v*(1-s)
        float qv  = value - svf;                  // v*(1-f*s)
        float tv  = vmin + svf;                   // v*(1-(1-f)*s)

        ro[j] = (hi == 0) ? v  : (hi == 1) ? qv : (hi == 2) ? pv
              : (hi == 3) ? pv : (hi == 4) ? tv : v;
        go[j] = (hi == 0) ? tv : (hi == 1) ? v  : (hi == 2) ? v
              : (hi == 3) ? qv : (hi == 4) ? pv : pv;
        bo[j] = (hi == 0) ? pv : (hi == 1) ? pv : (hi == 2) ? tv
              : (hi == 3) ? v  : (hi == 4) ? v  : qv;
    }

    // Single cold block: if ANY of the 4 pixels is in the wrap band,
    // recompute the whole quad with the bit-faithful exact path.
    if (__builtin_expect(band, 0)) {
#pragma unroll
        for (int j = 0; j < 4; ++j)
            hvi_exact(rin[j], gin[j], bin[j], k, ro[j], go[j], bo[j]);
    }

    float4 Ro = make_float4(ro[0], ro[1], ro[2], ro[3]);
    float4 Go = make_float4(go[0], go[1], go[2], go[3]);
    float4 Bo = make_float4(bo[0], bo[1], bo[2], bo[3]);

    *reinterpret_cast<float4*>(out + base)           = Ro;
    *reinterpret_cast<float4*>(out + base + 1048576) = Go;
    *reinterpret_cast<float4*>(out + base + 2097152) = Bo;
}

extern "C" void kernel_launch(void* const* d_in, const int* in_sizes, int n_in,
                              void* d_out, int out_size, void* d_ws, size_t ws_size,
                              hipStream_t stream)
{
    const float* img  = (const float*)d_in[0];
    const float* kptr = (const float*)d_in[1];
    float* out = (float*)d_out;

    int total   = in_sizes[0];        // 16*3*1024*1024 = 50331648
    int ngroups = total / 12;         // pixels/4 = 4194304
    int block   = 256;
    int grid    = (ngroups + block - 1) / block;

    rgb_hvi_kernel<<<grid, block, 0, stream>>>(img, kptr, out, ngroups);
}